// Round 3
// baseline (394.246 us; speedup 1.0000x reference)
//
#include <hip/hip_runtime.h>

// CustomQuantizer: idx = argmax(x, axis=-1); out[n, :] = W[:, idx[n]] = W.T[idx[n], :]
//   x: [8192, 8192] fp32, W: [1024, 8192] fp32, out: [8192, 1024] fp32
//
// R2 post-mortem: fixed harness overhead ~269 us (1GB ws poison + input
// restore); our kernels were ~122 us. Argmax kernel ran at ~3 TB/s: the
// compare chain serialized the 8 row loads (VGPR=32 -> ~2 in flight), and
// the 20 us transpose was serial. R3: (1) explicit 8x float4 prefetch
// before compares; (2) merge transpose into the argmax kernel (1-in-5
// blocks transpose a 64x64 tile, float4 both sides, 2-way-free LDS
// pattern), argmax writes idx to ws; (3) tiny gather kernel B afterwards
// (kernel boundary = WT-ready barrier).

#define QUANT_DIM 8192
#define OUT_DIM   1024
#define BLOCK     256
#define TT        64
#define TPAD      65
#define N_TTILES  ((QUANT_DIM / TT) * (OUT_DIM / TT))   // 128*16 = 2048
#define N_TOK_FAST 8192                                 // interleave assumes 4*N_TTILES

// ---------------- kernel A: interleaved W-transpose + row argmax ----------------
__global__ __launch_bounds__(BLOCK) void quantA(
    const float* __restrict__ x,
    const float* __restrict__ W,
    float* __restrict__ WT,
    int*  __restrict__ idx_out)
{
    __shared__ float lds[TT * TPAD];
    const int tid = threadIdx.x;
    const int b = blockIdx.x;

    if (b % 5 == 0) {
        // ---- transpose one 64x64 tile of W into WT ----
        const int tile = b / 5;
        const int bx = tile & (QUANT_DIM / TT - 1);   // quant tile (128)
        const int by = tile >> 7;                     // out tile (16)
        const int rr = tid >> 4;                      // 0..15
        const int c4 = tid & 15;                      // 0..15 (float4 col)
        #pragma unroll
        for (int it = 0; it < 4; ++it) {
            const int r = it * 16 + rr;               // out-row within tile
            const float4 v = *reinterpret_cast<const float4*>(
                W + (size_t)(by * TT + r) * QUANT_DIM + (bx * TT + c4 * 4));
            // transposed scalar stores: bank = (4*c4+k + rr + 16*it) % 32 -> 2-way (free)
            lds[(c4 * 4 + 0) * TPAD + r] = v.x;
            lds[(c4 * 4 + 1) * TPAD + r] = v.y;
            lds[(c4 * 4 + 2) * TPAD + r] = v.z;
            lds[(c4 * 4 + 3) * TPAD + r] = v.w;
        }
        __syncthreads();
        #pragma unroll
        for (int it = 0; it < 4; ++it) {
            const int q = it * 16 + rr;               // quant-row within tile
            float4 v;
            v.x = lds[q * TPAD + c4 * 4 + 0];
            v.y = lds[q * TPAD + c4 * 4 + 1];
            v.z = lds[q * TPAD + c4 * 4 + 2];
            v.w = lds[q * TPAD + c4 * 4 + 3];
            *reinterpret_cast<float4*>(
                WT + (size_t)(bx * TT + q) * OUT_DIM + (by * TT + c4 * 4)) = v;
        }
    } else {
        // ---- argmax of one x row ----
        const int row = b - b / 5 - 1;
        const float* xr = x + (size_t)row * QUANT_DIM;

        // prefetch ALL 8 float4s first -> 8 wave-loads in flight
        float4 v[8];
        #pragma unroll
        for (int i = 0; i < 8; ++i)
            v[i] = *reinterpret_cast<const float4*>(xr + i * (BLOCK * 4) + tid * 4);

        // per-thread indices increase with i -> strict '>' keeps FIRST max
        float best = -INFINITY;
        int bidx = 0;
        #pragma unroll
        for (int i = 0; i < 8; ++i) {
            const int base = i * (BLOCK * 4) + tid * 4;
            if (v[i].x > best) { best = v[i].x; bidx = base;     }
            if (v[i].y > best) { best = v[i].y; bidx = base + 1; }
            if (v[i].z > best) { best = v[i].z; bidx = base + 2; }
            if (v[i].w > best) { best = v[i].w; bidx = base + 3; }
        }

        // wave reduction, tie-break to smaller index
        #pragma unroll
        for (int off = 32; off > 0; off >>= 1) {
            const float ov = __shfl_down(best, off, 64);
            const int   oi = __shfl_down(bidx, off, 64);
            if (ov > best || (ov == best && oi < bidx)) { best = ov; bidx = oi; }
        }

        // cross-wave via LDS (reuse tile memory)
        float* sval = lds;
        int*   sidx = reinterpret_cast<int*>(lds + 8);
        const int wave = tid >> 6;
        if ((tid & 63) == 0) { sval[wave] = best; sidx[wave] = bidx; }
        __syncthreads();
        if (tid == 0) {
            float bb = sval[0];
            int   bi = sidx[0];
            #pragma unroll
            for (int w = 1; w < BLOCK / 64; ++w) {
                if (sval[w] > bb || (sval[w] == bb && sidx[w] < bi)) {
                    bb = sval[w]; bi = sidx[w];
                }
            }
            idx_out[row] = bi;
        }
    }
}

// ---------------- kernel B: coalesced gather out[n] = WT[idx[n]] ----------------
__global__ __launch_bounds__(BLOCK) void quantB(
    const float* __restrict__ WT,
    const int*  __restrict__ idx,
    float* __restrict__ out,
    int n_tokens)
{
    const int row = blockIdx.x * 4 + (threadIdx.x >> 6);   // wave per row
    if (row >= n_tokens) return;
    const int lane = threadIdx.x & 63;
    const int id = idx[row];
    const float4* src = reinterpret_cast<const float4*>(WT + (size_t)id * OUT_DIM);
    float4*       dst = reinterpret_cast<float4*>(out + (size_t)row * OUT_DIM);
    #pragma unroll
    for (int k = 0; k < 4; ++k)
        dst[lane + 64 * k] = src[lane + 64 * k];
}

// ---------------- generic fallbacks (non-8192 token count or tiny ws) ----------------
__global__ __launch_bounds__(BLOCK) void quantizer_fused_direct(
    const float* __restrict__ x,
    const float* __restrict__ W,
    float* __restrict__ out,
    int n_tokens)
{
    const int row = blockIdx.x;
    if (row >= n_tokens) return;
    const int tid = threadIdx.x;
    const float* xr = x + (size_t)row * QUANT_DIM;

    float4 v[8];
    #pragma unroll
    for (int i = 0; i < 8; ++i)
        v[i] = *reinterpret_cast<const float4*>(xr + i * (BLOCK * 4) + tid * 4);
    float best = -INFINITY;
    int bidx = 0;
    #pragma unroll
    for (int i = 0; i < 8; ++i) {
        const int base = i * (BLOCK * 4) + tid * 4;
        if (v[i].x > best) { best = v[i].x; bidx = base;     }
        if (v[i].y > best) { best = v[i].y; bidx = base + 1; }
        if (v[i].z > best) { best = v[i].z; bidx = base + 2; }
        if (v[i].w > best) { best = v[i].w; bidx = base + 3; }
    }
    #pragma unroll
    for (int off = 32; off > 0; off >>= 1) {
        const float ov = __shfl_down(best, off, 64);
        const int   oi = __shfl_down(bidx, off, 64);
        if (ov > best || (ov == best && oi < bidx)) { best = ov; bidx = oi; }
    }
    __shared__ float sval[BLOCK / 64];
    __shared__ int   sidx[BLOCK / 64];
    __shared__ int   result;
    const int wave = tid >> 6;
    if ((tid & 63) == 0) { sval[wave] = best; sidx[wave] = bidx; }
    __syncthreads();
    if (tid == 0) {
        float bb = sval[0];
        int   bi = sidx[0];
        #pragma unroll
        for (int w = 1; w < BLOCK / 64; ++w) {
            if (sval[w] > bb || (sval[w] == bb && sidx[w] < bi)) {
                bb = sval[w]; bi = sidx[w];
            }
        }
        result = bi;
    }
    __syncthreads();
    const int id = result;
    float* orow = out + (size_t)row * OUT_DIM;
    for (int j = tid; j < OUT_DIM; j += BLOCK) {
        orow[j] = W[(size_t)j * QUANT_DIM + id];
    }
}

extern "C" void kernel_launch(void* const* d_in, const int* in_sizes, int n_in,
                              void* d_out, int out_size, void* d_ws, size_t ws_size,
                              hipStream_t stream) {
    const float* x = (const float*)d_in[0];
    const float* W = (const float*)d_in[1];
    float* out = (float*)d_out;
    const int n_tokens = in_sizes[0] / QUANT_DIM;

    const size_t wt_bytes  = (size_t)QUANT_DIM * OUT_DIM * sizeof(float);
    const size_t idx_bytes = (size_t)n_tokens * sizeof(int);

    if (n_tokens == N_TOK_FAST && ws_size >= wt_bytes + idx_bytes) {
        float* WT  = (float*)d_ws;
        int*   idx = (int*)((char*)d_ws + wt_bytes);
        // grid = 8192 argmax + 2048 transpose blocks, interleaved 4:1
        quantA<<<N_TOK_FAST + N_TTILES, BLOCK, 0, stream>>>(x, W, WT, idx);
        quantB<<<N_TOK_FAST / 4, BLOCK, 0, stream>>>(WT, idx, out, n_tokens);
    } else {
        quantizer_fused_direct<<<n_tokens, BLOCK, 0, stream>>>(x, W, out, n_tokens);
    }
}